// Round 4
// baseline (407.113 us; speedup 1.0000x reference)
//
#include <hip/hip_runtime.h>
#include <hip/hip_bf16.h>
#include <cstdint>
#include <type_traits>

// LocalRNN: B=16 L=1024 D=256 H=256 K=16 (GRU over K-window per position).
// FP32 in/out. MFMA on bf16; fp32 gates + recurrence.
//   prep    : fuse x/W_ih bf16 cvt + W_hh wave-blocked repack + Gxt pad fill.
//   gx_gemm : Gxt[b][g][16+l] = (x W_ih^T + b_ih)[l][g]  (TRANSPOSED store).
//   rnn_main: 256 blocks x 1024 thr, 1 block/CU. gilT (768x80 bf16, transposed
//             gi slice) + h (64x264 bf16) in LDS; W streamed contiguously from
//             Wr with explicit next-k prefetch; 128-VGPR budget.

#define B_  16
#define L_  1024
#define D_  256
#define H_  256
#define K_  16
#define G3  768
#define LPP 1048           // padded l-extent of Gxt per (b,g): 16 pad + 1024 + slack
#define MT  64             // positions per block
#define HS  264            // h LDS row stride (u16)
#define GTS 80             // gilT LDS row stride (u16); 160 B -> 16B-aligned rows

typedef __attribute__((ext_vector_type(8))) short  bf16x8;
typedef __attribute__((ext_vector_type(4))) float  floatx4;
typedef unsigned short ush;

__device__ __forceinline__ ush f2bf(float f) {
    union { float f; unsigned int i; } v; v.f = f;
    unsigned int x = v.i;
    return (ush)((x + 0x7FFFu + ((x >> 16) & 1u)) >> 16);  // RNE
}
__device__ __forceinline__ unsigned int pk2(float a, float b) {
    union { __hip_bfloat162 v; unsigned int u; } c;
    c.v = __float22bfloat162_rn(make_float2(a, b));  // lo=a, hi=b
    return c.u;
}
__device__ __forceinline__ float rcpf(float x) { return __builtin_amdgcn_rcpf(x); }
__device__ __forceinline__ float fsig(float x) { return rcpf(1.f + __expf(-x)); }
__device__ __forceinline__ float ftanh_(float x) {
    return 1.f - 2.f * rcpf(__expf(2.f * x) + 1.f);  // exact limits at +-inf
}

// read 4 consecutive bf16 (u16 idx s..s+3) where p points at e = s - P0 (e even)
template<int P0>
__device__ __forceinline__ float4 ext4(const ush* p) {
    float4 o;
    unsigned int d0 = *(const unsigned int*)p;        // 4B-aligned
    unsigned int d1 = *(const unsigned int*)(p + 2);
    if constexpr (P0 == 0) {
        o.x = __uint_as_float(d0 << 16);
        o.y = __uint_as_float(d0 & 0xffff0000u);
        o.z = __uint_as_float(d1 << 16);
        o.w = __uint_as_float(d1 & 0xffff0000u);
    } else {
        unsigned int d2 = *(const unsigned int*)(p + 4);
        o.x = __uint_as_float(d0 & 0xffff0000u);
        o.y = __uint_as_float(d1 << 16);
        o.z = __uint_as_float(d1 & 0xffff0000u);
        o.w = __uint_as_float(d2 << 16);
    }
    return o;
}

// ---- fused prep: x cvt | W_ih cvt | W_hh wave-block repack | Gxt pad fill ---
#define NX4   1048576              // (B*L*D)/4
#define NW4   49152                // (G3*D)/4
#define NWR   196608               // G3*H
#define NPAD  196608               // B*G3*16
__global__ __launch_bounds__(256) void prep(const float* __restrict__ x,
                                            const float* __restrict__ Wih,
                                            const float* __restrict__ Whh,
                                            const float* __restrict__ bih,
                                            ush* __restrict__ xb,
                                            ush* __restrict__ Wbih,
                                            ush* __restrict__ Wr,
                                            ush* __restrict__ Gxt) {
    int idx = blockIdx.x * 256 + threadIdx.x;
    if (idx < NX4) {
        int i4 = idx * 4;
        float4 v = *(const float4*)(x + i4);
        *(uint2*)(xb + i4) = make_uint2(pk2(v.x, v.y), pk2(v.z, v.w));
    } else if (idx < NX4 + NW4) {
        int i4 = (idx - NX4) * 4;
        float4 v = *(const float4*)(Wih + i4);
        *(uint2*)(Wbih + i4) = make_uint2(pk2(v.x, v.y), pk2(v.z, v.w));
    } else if (idx < NX4 + NW4 + NWR) {
        int e = idx - NX4 - NW4;
        int w  = e / 12288, r1 = e % 12288;
        int ks = r1 / 1536, r2 = r1 % 1536;
        int gt = r2 / 512,  r3 = r2 % 512;
        int lane = r3 >> 3, j = r3 & 7;
        int l16 = lane & 15, quad = lane >> 4;
        int row = gt * 256 + w * 16 + l16;
        int col = ks * 32 + quad * 8 + j;
        Wr[e] = f2bf(Whh[row * 256 + col]);
    } else if (idx < NX4 + NW4 + NWR + NPAD) {
        int e = idx - NX4 - NW4 - NWR;
        int l = e & 15, bg = e >> 4;
        int g = bg % G3, b = bg / G3;
        Gxt[((size_t)b * G3 + g) * LPP + l] = f2bf(bih[g]);
    }
}

// ---- Gx GEMM: [16384,256] x [256,768], bias folded, transposed store -------
__global__ __launch_bounds__(256) void gx_gemm(const ush* __restrict__ xb,
                                               const ush* __restrict__ Wb,
                                               const float* __restrict__ b_ih,
                                               ush* __restrict__ Gxt) {
    int m0   = blockIdx.x * 64;
    int n0   = blockIdx.y * 64;
    int wave = threadIdx.x >> 6;
    int lane = threadIdx.x & 63;
    int l16  = lane & 15, quad = lane >> 4;

    const ush* xa = xb + (size_t)(m0 + wave * 16 + l16) * D_ + quad * 8;

    floatx4 acc[4];
    for (int nt = 0; nt < 4; nt++) {
        float bias = b_ih[n0 + nt * 16 + l16];
        acc[nt] = (floatx4){bias, bias, bias, bias};
    }
    for (int ks = 0; ks < 8; ks++) {
        bf16x8 afrag = *(const bf16x8*)(xa + ks * 32);
        for (int nt = 0; nt < 4; nt++) {
            const ush* wp = Wb + (size_t)(n0 + nt * 16 + l16) * D_ + ks * 32 + quad * 8;
            bf16x8 bfrag = *(const bf16x8*)wp;
            acc[nt] = __builtin_amdgcn_mfma_f32_16x16x32_bf16(afrag, bfrag, acc[nt], 0, 0, 0);
        }
    }
    // C/D: col = l16 -> gate col n; row = quad*4+r -> position m (4 consecutive)
    int m = m0 + wave * 16 + quad * 4;
    int b = m >> 10, l = m & 1023;
    for (int nt = 0; nt < 4; nt++) {
        int n = n0 + nt * 16 + l16;
        uint2 pk = make_uint2(pk2(acc[nt][0], acc[nt][1]), pk2(acc[nt][2], acc[nt][3]));
        *(uint2*)(Gxt + ((size_t)b * G3 + n) * LPP + 16 + l) = pk;  // 8B-aligned
    }
}

// ---- recurrent GRU kernel --------------------------------------------------
__global__ __launch_bounds__(1024, 4) void rnn_main(const ush* __restrict__ Gxt,
                                                    const ush* __restrict__ Wr,
                                                    const float* __restrict__ b_hh,
                                                    float* __restrict__ out) {
    __shared__ __align__(16) ush gilT[G3 * GTS];  // 122,880 B  transposed gi slice
    __shared__ __align__(16) ush hl[MT * HS];     //  33,792 B  (tot 156,672)

    int tid  = threadIdx.x;
    int wave = tid >> 6, lane = tid & 63;
    int l16  = lane & 15, quad = lane >> 4, quad4 = quad * 4;
    int p0   = blockIdx.x * MT;
    int bb   = p0 >> 10, l0 = p0 & 1023;
    int ci   = wave * 16 + l16;      // this thread's hidden column

    // preload gilT[g][j] = Gxt[bb][g][l0 + j], j = 0..79  (16B-aligned both sides)
    const ush* gsrc = Gxt + ((size_t)bb * G3) * LPP + l0;
    for (int idx = tid; idx < G3 * 10; idx += 1024) {
        int g = idx / 10, c = idx % 10;
        *(float4*)(gilT + g * GTS + c * 8) = *(const float4*)(gsrc + (size_t)g * LPP + c * 8);
    }
    for (int idx = tid; idx < MT * HS / 2; idx += 1024)
        ((unsigned int*)hl)[idx] = 0u;

    float bias_r = b_hh[ci], bias_z = b_hh[256 + ci], bias_n = b_hh[512 + ci];
    float hreg[16];
#pragma unroll
    for (int q = 0; q < 16; q++) hreg[q] = 0.f;

    const ush* wbase = Wr + wave * 12288 + lane * 8;  // wave's contiguous 24KB

    auto do_step = [&](int t, auto par) {
        constexpr int P0 = decltype(par)::value;  // s = 1+t+4k: t even -> P0=1
        __syncthreads();

        floatx4 acc[4][3];
#pragma unroll
        for (int mc = 0; mc < 4; mc++) {
            int e = 1 + t + mc * 16 + quad4 - P0;  // even
            float4 vr = ext4<P0>(gilT + ci * GTS + e);
            float4 vz = ext4<P0>(gilT + (256 + ci) * GTS + e);
            acc[mc][0] = (floatx4){bias_r + vr.x, bias_r + vr.y, bias_r + vr.z, bias_r + vr.w};
            acc[mc][1] = (floatx4){bias_z + vz.x, bias_z + vz.y, bias_z + vz.z, bias_z + vz.w};
            acc[mc][2] = (floatx4){bias_n, bias_n, bias_n, bias_n};
        }

        // gh = h * W_hh^T, K=256; contiguous per-wave W stream + 1-deep prefetch
        bf16x8 bw0, bw1, bw2;
        bf16x8 bn0 = *(const bf16x8*)(wbase);
        bf16x8 bn1 = *(const bf16x8*)(wbase + 512);
        bf16x8 bn2 = *(const bf16x8*)(wbase + 1024);
#pragma unroll
        for (int ks = 0; ks < 8; ks++) {
            bw0 = bn0; bw1 = bn1; bw2 = bn2;
            if (ks < 7) {
                const ush* p = wbase + (ks + 1) * 1536;
                bn0 = *(const bf16x8*)(p);
                bn1 = *(const bf16x8*)(p + 512);
                bn2 = *(const bf16x8*)(p + 1024);
            }
#pragma unroll
            for (int mc = 0; mc < 4; mc++) {
                bf16x8 af = *(const bf16x8*)(hl + (mc * 16 + l16) * HS + ks * 32 + quad * 8);
                acc[mc][0] = __builtin_amdgcn_mfma_f32_16x16x32_bf16(af, bw0, acc[mc][0], 0, 0, 0);
                acc[mc][1] = __builtin_amdgcn_mfma_f32_16x16x32_bf16(af, bw1, acc[mc][1], 0, 0, 0);
                acc[mc][2] = __builtin_amdgcn_mfma_f32_16x16x32_bf16(af, bw2, acc[mc][2], 0, 0, 0);
            }
        }

        // gates; C/D: col=l16 -> ci, row=quad4+r -> position
#pragma unroll
        for (int mc = 0; mc < 4; mc++) {
            int e = 1 + t + mc * 16 + quad4 - P0;
            float4 vn = ext4<P0>(gilT + (512 + ci) * GTS + e);
            float inn[4] = {vn.x, vn.y, vn.z, vn.w};
#pragma unroll
            for (int r = 0; r < 4; r++) {
                int q = mc * 4 + r;
                float rg = fsig(acc[mc][0][r]);
                float zg = fsig(acc[mc][1][r]);
                float ng = ftanh_(inn[r] + rg * acc[mc][2][r]);
                hreg[q] = ng + zg * (hreg[q] - ng);
            }
        }
        __syncthreads();  // all A-frag reads for step t complete
#pragma unroll
        for (int mc = 0; mc < 4; mc++) {
            int mb = mc * 16 + quad4;
            unsigned int pa = pk2(hreg[mc * 4 + 0], hreg[mc * 4 + 1]);
            unsigned int pb = pk2(hreg[mc * 4 + 2], hreg[mc * 4 + 3]);
            hl[(mb + 0) * HS + ci] = (ush)(pa & 0xffffu);
            hl[(mb + 1) * HS + ci] = (ush)(pa >> 16);
            hl[(mb + 2) * HS + ci] = (ush)(pb & 0xffffu);
            hl[(mb + 3) * HS + ci] = (ush)(pb >> 16);
        }
    };

    for (int tt = 0; tt < 8; tt++) {
        do_step(2 * tt,     std::integral_constant<int, 1>{});
        do_step(2 * tt + 1, std::integral_constant<int, 0>{});
    }

#pragma unroll
    for (int mc = 0; mc < 4; mc++)
#pragma unroll
        for (int r = 0; r < 4; r++)
            out[(size_t)(p0 + mc * 16 + quad4 + r) * H_ + ci] = hreg[mc * 4 + r];
}

extern "C" void kernel_launch(void* const* d_in, const int* in_sizes, int n_in,
                              void* d_out, int out_size, void* d_ws, size_t ws_size,
                              hipStream_t stream) {
    const float* x    = (const float*)d_in[0];
    const float* W_ih = (const float*)d_in[1];
    const float* W_hh = (const float*)d_in[2];
    const float* b_ih = (const float*)d_in[3];
    const float* b_hh = (const float*)d_in[4];
    float* out = (float*)d_out;

    // ws layout (bytes):
    //   Gxt   : B*G3*LPP bf16 = 25,755,648
    //   xb    : B*L*D bf16    =  8,388,608
    //   Wb_ih : G3*D bf16     =    393,216
    //   Wr    : G3*H bf16     =    393,216   (wave-blocked W_hh)
    char* ws = (char*)d_ws;
    ush* Gxt   = (ush*)ws;
    ush* xb    = (ush*)(ws + 25755648);
    ush* Wbih  = (ush*)(ws + 25755648 + 8388608);
    ush* Wr    = (ush*)(ws + 25755648 + 8388608 + 393216);

    prep<<<(NX4 + NW4 + NWR + NPAD) / 256, 256, 0, stream>>>(x, W_ih, W_hh, b_ih,
                                                             xb, Wbih, Wr, Gxt);
    dim3 g1(B_ * L_ / 64, G3 / 64);  // 256 x 12
    gx_gemm<<<g1, 256, 0, stream>>>(xb, Wbih, b_ih, Gxt);
    rnn_main<<<B_ * L_ / MT, 1024, 0, stream>>>(Gxt, Wr, b_hh, out);
}

// Round 5
// 268.792 us; speedup vs baseline: 1.5146x; 1.5146x over previous
//
#include <hip/hip_runtime.h>
#include <hip/hip_bf16.h>
#include <cstdint>

// LocalRNN: B=16 L=1024 D=256 H=256 K=16 (GRU over K-window per position).
// FP32 in/out. MFMA on bf16; fp32 gates + recurrence.
// Round-5 structure: W_hh REGISTER-RESIDENT (no per-step W stream).
//   prep    : W_ih cvt | W_hh repack into per-wave register-load layout |
//             Gp pad rows (bias-only cells).
//   gx_gemm : Gp[b][15+l][h] = u64 cell {rz-packed(+b_hh folded), n(+b_ih)}.
//   rnn_main: 1024 blocks x 512 thr (8 waves, 2/SIMD, 256-VGPR cap). Each
//             wave holds 6 B-frags x 8 ks of W_hh in 192 VGPRs across all 16
//             steps. gi slice (31 rows x 256 u64 = 63.5 KB) + h (16x264 bf16)
//             in LDS. Per step: LDS + regs only; zero global traffic.

#define B_  16
#define L_  1024
#define D_  256
#define H_  256
#define K_  16
#define LP  (L_ + K_ - 1)  // 1039 padded rows per batch (15 pad + 1024)
#define MT  16             // positions per rnn block
#define HS  264            // h LDS row stride (u16)

typedef __attribute__((ext_vector_type(8))) short  bf16x8;
typedef __attribute__((ext_vector_type(4))) float  floatx4;
typedef unsigned short ush;

__device__ __forceinline__ ush f2bf(float f) {
    union { float f; unsigned int i; } v; v.f = f;
    unsigned int x = v.i;
    return (ush)((x + 0x7FFFu + ((x >> 16) & 1u)) >> 16);  // RNE
}
__device__ __forceinline__ unsigned int pk2(float a, float b) {
    union { __hip_bfloat162 v; unsigned int u; } c;
    c.v = __float22bfloat162_rn(make_float2(a, b));  // lo=a, hi=b
    return c.u;
}
__device__ __forceinline__ float rcpf(float x) { return __builtin_amdgcn_rcpf(x); }
__device__ __forceinline__ float fsig(float x) { return rcpf(1.f + __expf(-x)); }
__device__ __forceinline__ float ftanh_(float x) {
    return 1.f - 2.f * rcpf(__expf(2.f * x) + 1.f);  // exact limits at +-inf
}

// ---- prep: W_ih cvt | W_hh register-layout repack | Gp pad rows ------------
#define NW4   49152    // (768*256)/4 W_ih float4 chunks
#define NWR   196608   // 768*256 W_hh elements
#define NPAD  61440    // 16 batches * 15 rows * 256 cols
__global__ __launch_bounds__(256) void prep(const float* __restrict__ Wih,
                                            const float* __restrict__ Whh,
                                            const float* __restrict__ bih,
                                            const float* __restrict__ bhh,
                                            ush* __restrict__ Wbih,
                                            ush* __restrict__ Wr,
                                            uint2* __restrict__ Gp) {
    int idx = blockIdx.x * 256 + threadIdx.x;
    if (idx < NW4) {
        int i4 = idx * 4;
        float4 v = *(const float4*)(Wih + i4);
        *(uint2*)(Wbih + i4) = make_uint2(pk2(v.x, v.y), pk2(v.z, v.w));
    } else if (idx < NW4 + NWR) {
        int e = idx - NW4;
        int w    = e / 24576, r1 = e % 24576;   // wave
        int n    = r1 / 4096,  r2 = r1 % 4096;  // frag = gate*2 + sloc
        int ks   = r2 / 512,   r3 = r2 % 512;
        int lane = r3 >> 3,    j  = r3 & 7;
        int l16 = lane & 15, quad = lane >> 4;
        int gate = n >> 1, sloc = n & 1;
        int srow = gate * 256 + (2 * w + sloc) * 16 + l16;
        int scol = ks * 32 + quad * 8 + j;
        Wr[e] = f2bf(Whh[srow * 256 + scol]);
    } else if (idx < NW4 + NWR + NPAD) {
        int e = idx - NW4 - NWR;
        int col = e & 255, rb = e >> 8;
        int row = rb % 15, b = rb / 15;
        uint2 cell;
        cell.x = pk2(bih[col] + bhh[col], bih[256 + col] + bhh[256 + col]);
        cell.y = (unsigned int)f2bf(bih[512 + col]);
        Gp[((size_t)b * LP + row) * 256 + col] = cell;
    }
}

// ---- Gx GEMM: all 3 gates for a 64-col hidden tile, u64-cell packed --------
__global__ __launch_bounds__(256, 4) void gx_gemm(const float* __restrict__ x,
                                                  const ush* __restrict__ Wb,
                                                  const float* __restrict__ bih,
                                                  const float* __restrict__ bhh,
                                                  uint2* __restrict__ Gp) {
    int m0   = blockIdx.x * 64;
    int n0   = blockIdx.y * 64;   // hidden-col tile base (0,64,128,192)
    int wave = threadIdx.x >> 6;
    int lane = threadIdx.x & 63;
    int l16  = lane & 15, quad = lane >> 4;

    const float* xa = x + (size_t)(m0 + wave * 16 + l16) * D_ + quad * 8;

    floatx4 acc[12];  // [gate*4 + stripe]
#pragma unroll
    for (int g = 0; g < 3; g++)
#pragma unroll
        for (int st = 0; st < 4; st++) {
            int gcol = g * 256 + n0 + st * 16 + l16;
            float b = bih[gcol] + (g < 2 ? bhh[gcol] : 0.f);  // fold b_hh for r,z
            acc[g * 4 + st] = (floatx4){b, b, b, b};
        }
#pragma unroll
    for (int ks = 0; ks < 8; ks++) {
        float4 a0 = *(const float4*)(xa + ks * 32);
        float4 a1 = *(const float4*)(xa + ks * 32 + 4);
        union { uint4 u; bf16x8 v; } af;
        af.u = make_uint4(pk2(a0.x, a0.y), pk2(a0.z, a0.w),
                          pk2(a1.x, a1.y), pk2(a1.z, a1.w));
#pragma unroll
        for (int g = 0; g < 3; g++)
#pragma unroll
            for (int st = 0; st < 4; st++) {
                const ush* wp = Wb + (size_t)(g * 256 + n0 + st * 16 + l16) * D_
                                + ks * 32 + quad * 8;
                acc[g * 4 + st] = __builtin_amdgcn_mfma_f32_16x16x32_bf16(
                    af.v, *(const bf16x8*)wp, acc[g * 4 + st], 0, 0, 0);
            }
    }
    // C/D: col = l16 -> hidden col; row = quad*4 + r -> position
    int m  = m0 + wave * 16 + quad * 4;
    int bb = m >> 10, lb = m & 1023;
#pragma unroll
    for (int st = 0; st < 4; st++) {
        int hcol = n0 + st * 16 + l16;
        uint2* dst = Gp + ((size_t)bb * LP + 15 + lb) * 256 + hcol;
#pragma unroll
        for (int r = 0; r < 4; r++) {
            uint2 cell;
            cell.x = (unsigned int)f2bf(acc[st][r])
                   | ((unsigned int)f2bf(acc[4 + st][r]) << 16);
            cell.y = (unsigned int)f2bf(acc[8 + st][r]);
            dst[(size_t)r * 256] = cell;
        }
    }
}

// ---- recurrent GRU kernel: W in registers ----------------------------------
__global__ __launch_bounds__(512, 2) void rnn_main(const uint2* __restrict__ Gp,
                                                   const ush* __restrict__ Wr,
                                                   const float* __restrict__ bhh,
                                                   float* __restrict__ out) {
    __shared__ uint2 gil[31 * 256];          // 63,488 B: gi cells rows p0..p0+30
    __shared__ __align__(16) ush hl[MT * HS];  // 8,448 B

    int tid  = threadIdx.x;
    int wave = tid >> 6, lane = tid & 63;
    int l16  = lane & 15, quad = lane >> 4, quad4 = quad * 4;
    int p0   = blockIdx.x * MT;
    int bb   = p0 >> 10, lb = p0 & 1023;
    int base = wave * 32 + l16;              // thread's first hidden col

    // ---- W_hh fragments -> 192 VGPRs (held across all 16 steps)
    bf16x8 wf[6][8];
    {
        const ush* wp = Wr + (size_t)wave * 24576 + lane * 8;
#pragma unroll
        for (int n = 0; n < 6; n++)
#pragma unroll
            for (int ks = 0; ks < 8; ks++)
                wf[n][ks] = *(const bf16x8*)(wp + ((n * 8 + ks) << 9));
    }
    // ---- preload gi slice (contiguous 63.5 KB) + zero h
    {
        const float4* gsrc = (const float4*)(Gp + (size_t)(bb * LP + lb) * 256);
        for (int idx = tid; idx < 31 * 256 / 2; idx += 512)
            ((float4*)gil)[idx] = gsrc[idx];
        for (int idx = tid; idx < MT * HS / 2; idx += 512)
            ((unsigned int*)hl)[idx] = 0u;
    }
    float bn0 = bhh[512 + base], bn1 = bhh[512 + base + 16];
    float hreg[8];
#pragma unroll
    for (int q = 0; q < 8; q++) hreg[q] = 0.f;

    for (int t = 0; t < K_; t++) {
        __syncthreads();  // h(t-1) writes (and initial fill) visible

        floatx4 acc[6];  // [gate*2 + sloc]
        acc[0] = acc[1] = acc[2] = acc[3] = (floatx4){0.f, 0.f, 0.f, 0.f};
        acc[4] = (floatx4){bn0, bn0, bn0, bn0};
        acc[5] = (floatx4){bn1, bn1, bn1, bn1};

        // gh = h * W_hh^T : A from LDS, B from registers
#pragma unroll
        for (int ks = 0; ks < 8; ks++) {
            bf16x8 af = *(const bf16x8*)(hl + l16 * HS + ks * 32 + quad * 8);
            acc[0] = __builtin_amdgcn_mfma_f32_16x16x32_bf16(af, wf[0][ks], acc[0], 0, 0, 0);
            acc[1] = __builtin_amdgcn_mfma_f32_16x16x32_bf16(af, wf[1][ks], acc[1], 0, 0, 0);
            acc[2] = __builtin_amdgcn_mfma_f32_16x16x32_bf16(af, wf[2][ks], acc[2], 0, 0, 0);
            acc[3] = __builtin_amdgcn_mfma_f32_16x16x32_bf16(af, wf[3][ks], acc[3], 0, 0, 0);
            acc[4] = __builtin_amdgcn_mfma_f32_16x16x32_bf16(af, wf[4][ks], acc[4], 0, 0, 0);
            acc[5] = __builtin_amdgcn_mfma_f32_16x16x32_bf16(af, wf[5][ks], acc[5], 0, 0, 0);
        }
        // gates; C/D: col=l16 -> base(+16), row=quad4+r -> position
#pragma unroll
        for (int sl = 0; sl < 2; sl++) {
            int c = base + sl * 16;
#pragma unroll
            for (int r = 0; r < 4; r++) {
                uint2 g = gil[(quad4 + r + t) * 256 + c];
                float rg = fsig(acc[0 + sl][r] + __uint_as_float(g.x << 16));
                float zg = fsig(acc[2 + sl][r] + __uint_as_float(g.x & 0xffff0000u));
                float ng = ftanh_(__uint_as_float(g.y << 16) + rg * acc[4 + sl][r]);
                int q = sl * 4 + r;
                hreg[q] = ng + zg * (hreg[q] - ng);
            }
        }
        __syncthreads();  // all A-frag reads of step t complete
#pragma unroll
        for (int sl = 0; sl < 2; sl++)
#pragma unroll
            for (int r = 0; r < 4; r++)
                hl[(quad4 + r) * HS + base + sl * 16] = f2bf(hreg[sl * 4 + r]);
    }
    // final h -> out (fp32)
#pragma unroll
    for (int sl = 0; sl < 2; sl++)
#pragma unroll
        for (int r = 0; r < 4; r++)
            out[(size_t)(p0 + quad4 + r) * H_ + base + sl * 16] = hreg[sl * 4 + r];
}

extern "C" void kernel_launch(void* const* d_in, const int* in_sizes, int n_in,
                              void* d_out, int out_size, void* d_ws, size_t ws_size,
                              hipStream_t stream) {
    const float* x    = (const float*)d_in[0];
    const float* W_ih = (const float*)d_in[1];
    const float* W_hh = (const float*)d_in[2];
    const float* b_ih = (const float*)d_in[3];
    const float* b_hh = (const float*)d_in[4];
    float* out = (float*)d_out;

    // ws layout (bytes):
    //   Gp   : B*LP*256 u64 cells = 34,045,952
    //   Wbih : 768*256 bf16      =    393,216
    //   Wr   : 768*256 bf16      =    393,216
    char* ws = (char*)d_ws;
    uint2* Gp  = (uint2*)ws;
    ush* Wbih  = (ush*)(ws + 34045952);
    ush* Wr    = (ush*)(ws + 34045952 + 393216);

    prep<<<(NW4 + NWR + NPAD + 255) / 256, 256, 0, stream>>>(W_ih, W_hh, b_ih, b_hh,
                                                             Wbih, Wr, Gp);
    dim3 g1(B_ * L_ / 64, 4);  // 256 x 4 hidden-col tiles
    gx_gemm<<<g1, 256, 0, stream>>>(x, Wbih, b_ih, b_hh, Gp);
    rnn_main<<<B_ * L_ / MT, 512, 0, stream>>>(Gp, Wr, b_hh, out);
}

// Round 6
// 243.442 us; speedup vs baseline: 1.6723x; 1.1041x over previous
//
#include <hip/hip_runtime.h>
#include <hip/hip_bf16.h>
#include <cstdint>

// LocalRNN: B=16 L=1024 D=256 H=256 K=16 (GRU over K-window per position).
// FP32 in/out. MFMA on bf16; fp32 gates + recurrence.
// Round-6: W_hh register-resident + MT=32 (2x16 sub-tiles, 4 quarter-steps),
// double-buffered h (ONE barrier/step), exp2 scale-folding (r,z pre-scaled by
// -log2e; n by 2*log2e => raw v_exp_f32 per gate), Grz/Gn split gi arrays.

#define B_  16
#define L_  1024
#define D_  256
#define H_  256
#define K_  16
#define LP  (L_ + K_ - 1)  // 1039 padded rows per batch (15 pad + 1024)
#define MT  32             // positions per rnn block
#define NROW 47            // gi rows per block = MT + K - 1
#define HS  264            // h LDS row stride (u16)
#define GRS 258            // grz LDS row stride (u32): 2-bank row shift
#define GNS 264            // gn LDS row stride (u16)
#define L2E 1.44269504f

typedef __attribute__((ext_vector_type(8))) short  bf16x8;
typedef __attribute__((ext_vector_type(4))) float  floatx4;
typedef unsigned short ush;

#if __has_builtin(__builtin_amdgcn_exp2f)
#define fexp2(x) __builtin_amdgcn_exp2f(x)
#else
#define fexp2(x) exp2f(x)
#endif

__device__ __forceinline__ float bf2f(ush u) {
    union { unsigned int i; float f; } v; v.i = ((unsigned int)u) << 16; return v.f;
}
__device__ __forceinline__ ush f2bf(float f) {
    union { float f; unsigned int i; } v; v.f = f;
    unsigned int x = v.i;
    return (ush)((x + 0x7FFFu + ((x >> 16) & 1u)) >> 16);  // RNE
}
__device__ __forceinline__ unsigned int pk2(float a, float b) {
    union { __hip_bfloat162 v; unsigned int u; } c;
    c.v = __float22bfloat162_rn(make_float2(a, b));  // lo=a, hi=b
    return c.u;
}
__device__ __forceinline__ float rcpf(float x) { return __builtin_amdgcn_rcpf(x); }

// ---- prep: x cvt | W_ih cvt | W_hh repack (scaled) | pad rows --------------
#define NX4   1048576  // (B*L*D)/4
#define NW4   49152    // (768*256)/4
#define NWR   196608   // 768*256
#define NPAD  61440    // 16*15*256
__global__ __launch_bounds__(256) void prep(const float* __restrict__ x,
                                            const float* __restrict__ Wih,
                                            const float* __restrict__ Whh,
                                            const float* __restrict__ bih,
                                            const float* __restrict__ bhh,
                                            ush* __restrict__ xb,
                                            ush* __restrict__ Wbih,
                                            ush* __restrict__ Wr,
                                            unsigned int* __restrict__ Grz_g,
                                            ush* __restrict__ Gn_g) {
    int idx = blockIdx.x * 256 + threadIdx.x;
    if (idx < NX4) {
        int i4 = idx * 4;
        float4 v = *(const float4*)(x + i4);
        *(uint2*)(xb + i4) = make_uint2(pk2(v.x, v.y), pk2(v.z, v.w));
    } else if (idx < NX4 + NW4) {
        int i4 = (idx - NX4) * 4;
        float4 v = *(const float4*)(Wih + i4);
        *(uint2*)(Wbih + i4) = make_uint2(pk2(v.x, v.y), pk2(v.z, v.w));
    } else if (idx < NX4 + NW4 + NWR) {
        int e = idx - NX4 - NW4;
        int w    = e / 24576, r1 = e % 24576;   // wave
        int n    = r1 / 4096,  r2 = r1 % 4096;  // frag = gate*2 + sloc
        int ks   = r2 / 512,   r3 = r2 % 512;
        int lane = r3 >> 3,    j  = r3 & 7;
        int l16 = lane & 15, quad = lane >> 4;
        int gate = n >> 1, sloc = n & 1;
        int srow = gate * 256 + (2 * w + sloc) * 16 + l16;
        int scol = ks * 32 + quad * 8 + j;
        float scl = (gate < 2) ? -L2E : 2.f * L2E;
        Wr[e] = f2bf(Whh[srow * 256 + scol] * scl);
    } else if (idx < NX4 + NW4 + NWR + NPAD) {
        int e = idx - NX4 - NW4 - NWR;
        int col = e & 255, rb = e >> 8;
        int row = rb % 15, b = rb / 15;
        size_t o = ((size_t)b * LP + row) * 256 + col;
        Grz_g[o] = pk2(-L2E * (bih[col] + bhh[col]),
                       -L2E * (bih[256 + col] + bhh[256 + col]));
        Gn_g[o]  = f2bf(2.f * L2E * bih[512 + col]);
    }
}

// ---- Gx GEMM: m=128/block, one 64-col hidden tile, scaled split store ------
__global__ __launch_bounds__(512) void gx_gemm(const ush* __restrict__ xb,
                                               const ush* __restrict__ Wb,
                                               const float* __restrict__ bih,
                                               const float* __restrict__ bhh,
                                               unsigned int* __restrict__ Grz_g,
                                               ush* __restrict__ Gn_g) {
    int m0   = blockIdx.x * 128;
    int n0   = blockIdx.y * 64;
    int tid  = threadIdx.x;
    int wave = tid >> 6, lane = tid & 63;
    int l16  = lane & 15, quad = lane >> 4, quad4 = quad * 4;

    const ush* xa = xb + (size_t)(m0 + wave * 16 + l16) * D_ + quad * 8;

    floatx4 acc[12];  // [gate*4 + stripe]
#pragma unroll
    for (int g = 0; g < 3; g++)
#pragma unroll
        for (int st = 0; st < 4; st++) {
            int gcol = g * 256 + n0 + st * 16 + l16;
            float b = bih[gcol] + (g < 2 ? bhh[gcol] : 0.f);
            acc[g * 4 + st] = (floatx4){b, b, b, b};
        }
#pragma unroll
    for (int ks = 0; ks < 8; ks++) {
        bf16x8 af = *(const bf16x8*)(xa + ks * 32);
#pragma unroll
        for (int g = 0; g < 3; g++)
#pragma unroll
            for (int st = 0; st < 4; st++) {
                const ush* wp = Wb + (size_t)(g * 256 + n0 + st * 16 + l16) * D_
                                + ks * 32 + quad * 8;
                acc[g * 4 + st] = __builtin_amdgcn_mfma_f32_16x16x32_bf16(
                    af, *(const bf16x8*)wp, acc[g * 4 + st], 0, 0, 0);
            }
    }
    // C/D: col=l16 -> hidden col; row=quad4+r -> position
    int m  = m0 + wave * 16 + quad4;
    int bb = m >> 10, lbr = (m & 1023) + 15;
    size_t rowb = (size_t)bb * LP + lbr;
#pragma unroll
    for (int st = 0; st < 4; st++) {
        int hcol = n0 + st * 16 + l16;
#pragma unroll
        for (int r = 0; r < 4; r++) {
            Grz_g[(rowb + r) * 256 + hcol] =
                pk2(-L2E * acc[st][r], -L2E * acc[4 + st][r]);
            Gn_g[(rowb + r) * 256 + hcol] = f2bf(2.f * L2E * acc[8 + st][r]);
        }
    }
}

// ---- recurrent GRU kernel: W in registers, MT=32, 1 barrier/step -----------
__global__ __launch_bounds__(512, 2) void rnn_main(const unsigned int* __restrict__ Grz_g,
                                                   const ush* __restrict__ Gn_g,
                                                   const ush* __restrict__ Wr,
                                                   const float* __restrict__ bhh,
                                                   float* __restrict__ out) {
    __shared__ unsigned int grz[NROW * GRS];        // 48,504 B
    __shared__ __align__(16) ush gn[NROW * GNS];    // 24,816 B
    __shared__ __align__(16) ush hl[2][MT * HS];    // 33,792 B  (tot 107,112)

    int tid  = threadIdx.x;
    int wave = tid >> 6, lane = tid & 63;
    int l16  = lane & 15, quad = lane >> 4, quad4 = quad * 4;
    int p0   = blockIdx.x * MT;
    int bb   = p0 >> 10, lb = p0 & 1023;
    int base = wave * 32 + l16;               // thread's first hidden col

    // W_hh fragments (scaled) -> 192 regs, held across all 16 steps
    bf16x8 wf[6][8];
    {
        const ush* wp = Wr + (size_t)wave * 24576 + lane * 8;
#pragma unroll
        for (int n = 0; n < 6; n++)
#pragma unroll
            for (int ks = 0; ks < 8; ks++)
                wf[n][ks] = *(const bf16x8*)(wp + ((n * 8 + ks) << 9));
    }
    // preload gi slices + zero h buffer 0
    {
        const uint2* s1 = (const uint2*)(Grz_g + ((size_t)(bb * LP) + lb) * 256);
        for (int idx = tid; idx < NROW * 128; idx += 512) {
            int row = idx >> 7, c = idx & 127;
            *(uint2*)(grz + row * GRS + c * 2) = s1[row * 128 + c];
        }
        const float4* s2 = (const float4*)(Gn_g + ((size_t)(bb * LP) + lb) * 256);
        for (int idx = tid; idx < NROW * 32; idx += 512) {
            int row = idx >> 5, c = idx & 31;
            *(float4*)(gn + row * GNS + c * 8) = s2[row * 32 + c];
        }
        for (int idx = tid; idx < MT * HS / 2; idx += 512)
            ((unsigned int*)(&hl[0][0]))[idx] = 0u;
    }
    float bn0 = 2.f * L2E * bhh[512 + base];
    float bn1 = 2.f * L2E * bhh[512 + base + 16];
    __syncthreads();

    for (int t = 0; t < K_; t++) {
        const ush* hc  = &hl[t & 1][0];
        ush*       hnx = &hl[(t + 1) & 1][0];
#pragma unroll
        for (int T = 0; T < 2; T++) {
#pragma unroll
            for (int sl = 0; sl < 2; sl++) {
                int col = base + sl * 16;
                int r0  = T * 16 + quad4 + t;
                // prefetch rz cells (LDS latency hidden by MFMA loop)
                unsigned int c0 = grz[(r0 + 0) * GRS + col];
                unsigned int c1 = grz[(r0 + 1) * GRS + col];
                unsigned int c2 = grz[(r0 + 2) * GRS + col];
                unsigned int c3 = grz[(r0 + 3) * GRS + col];
                float bn = sl ? bn1 : bn0;
                floatx4 a0 = (floatx4){0.f, 0.f, 0.f, 0.f};
                floatx4 a1 = (floatx4){0.f, 0.f, 0.f, 0.f};
                floatx4 a2 = (floatx4){bn, bn, bn, bn};
                const ush* ha = hc + (T * 16 + l16) * HS + quad * 8;
#pragma unroll
                for (int ks = 0; ks < 8; ks++) {
                    bf16x8 af = *(const bf16x8*)(ha + ks * 32);
                    a0 = __builtin_amdgcn_mfma_f32_16x16x32_bf16(af, wf[0 + sl][ks], a0, 0, 0, 0);
                    a1 = __builtin_amdgcn_mfma_f32_16x16x32_bf16(af, wf[2 + sl][ks], a1, 0, 0, 0);
                    a2 = __builtin_amdgcn_mfma_f32_16x16x32_bf16(af, wf[4 + sl][ks], a2, 0, 0, 0);
                }
                unsigned int cc[4] = {c0, c1, c2, c3};
                int hb = (T * 16 + quad4) * HS + col;
#pragma unroll
                for (int r = 0; r < 4; r++) {
                    float ar = a0[r] + __uint_as_float(cc[r] << 16);
                    float az = a1[r] + __uint_as_float(cc[r] & 0xffff0000u);
                    float rg = rcpf(1.f + fexp2(ar));   // sigmoid (pre-scaled -log2e)
                    float zg = rcpf(1.f + fexp2(az));
                    float u  = bf2f(gn[(r0 + r) * GNS + col]) + rg * a2[r];
                    float ng = 1.f - 2.f * rcpf(fexp2(u) + 1.f);  // tanh (pre-scaled 2log2e)
                    float ho = bf2f(hc[hb + r * HS]);
                    float hv = ng + zg * (ho - ng);
                    hnx[hb + r * HS] = f2bf(hv);
                }
            }
        }
        __syncthreads();  // single barrier: next step reads hnx
    }
    // final h lives in hl[0] (step 15 wrote buffer (15+1)&1 = 0); own cells
#pragma unroll
    for (int T = 0; T < 2; T++)
#pragma unroll
        for (int sl = 0; sl < 2; sl++)
#pragma unroll
            for (int r = 0; r < 4; r++) {
                int row = T * 16 + quad4 + r, col = base + sl * 16;
                out[(size_t)(p0 + row) * H_ + col] = bf2f(hl[0][row * HS + col]);
            }
}

extern "C" void kernel_launch(void* const* d_in, const int* in_sizes, int n_in,
                              void* d_out, int out_size, void* d_ws, size_t ws_size,
                              hipStream_t stream) {
    const float* x    = (const float*)d_in[0];
    const float* W_ih = (const float*)d_in[1];
    const float* W_hh = (const float*)d_in[2];
    const float* b_ih = (const float*)d_in[3];
    const float* b_hh = (const float*)d_in[4];
    float* out = (float*)d_out;

    // ws layout (bytes):
    //   Grz_g : B*LP*256 u32  = 17,022,976
    //   Gn_g  : B*LP*256 u16  =  8,511,488
    //   xb    : B*L*D bf16    =  8,388,608
    //   Wbih  : 768*256 bf16  =    393,216
    //   Wr    : 768*256 bf16  =    393,216   (scaled, wave-blocked W_hh)
    char* ws = (char*)d_ws;
    unsigned int* Grz_g = (unsigned int*)ws;
    ush* Gn_g = (ush*)(ws + 17022976);
    ush* xb   = (ush*)(ws + 17022976 + 8511488);
    ush* Wbih = (ush*)(ws + 17022976 + 8511488 + 8388608);
    ush* Wr   = (ush*)(ws + 17022976 + 8511488 + 8388608 + 393216);

    prep<<<(NX4 + NW4 + NWR + NPAD) / 256, 256, 0, stream>>>(
        x, W_ih, W_hh, b_ih, b_hh, xb, Wbih, Wr, Grz_g, Gn_g);
    dim3 g1(B_ * L_ / 128, 4);  // 128 x 4
    gx_gemm<<<g1, 512, 0, stream>>>(xb, Wbih, b_ih, b_hh, Grz_g, Gn_g);
    rnn_main<<<B_ * L_ / MT, 512, 0, stream>>>(Grz_g, Gn_g, Wr, b_hh, out);
}

// Round 7
// 190.182 us; speedup vs baseline: 2.1406x; 1.2800x over previous
//
#include <hip/hip_runtime.h>
#include <hip/hip_bf16.h>
#include <cstdint>

// LocalRNN: B=16 L=1024 D=256 H=256 K=16 (GRU over K-window per position).
// FP32 in/out. Round-7: FULLY FUSED. One tiny weight-repack kernel + one
// rnn_fused kernel (512 blocks x 512 thr):
//   - stage 48 x-rows (fp32->bf16, zero-padded) into LDS
//   - in-block gi GEMM (x * W_ih^T, scale-folded, bias-folded) -> grz/gn LDS
//   - 16 GRU steps: W_hh register-resident (192 VGPRs/wave), double-buffered
//     h in LDS, ONE barrier/step, h-old in registers, exp2-folded gates.
// Scale folding: r,z channels pre-scaled by -log2e, n by 2*log2e (in both
// repacked weights and bias init) => each gate is raw v_exp_f32 + v_rcp.

#define B_  16
#define L_  1024
#define D_  256
#define H_  256
#define K_  16
#define MT  32             // positions per block
#define NROW 47            // gi rows per block = MT + K - 1
#define HS  264            // h/xs LDS row stride (u16)
#define GRS 258            // grz LDS row stride (u32): 2-bank row shift
#define GNS 264            // gn LDS row stride (u16)
#define L2E 1.44269504f

typedef __attribute__((ext_vector_type(8))) short  bf16x8;
typedef __attribute__((ext_vector_type(4))) float  floatx4;
typedef unsigned short ush;

#if __has_builtin(__builtin_amdgcn_exp2f)
#define fexp2(x) __builtin_amdgcn_exp2f(x)
#else
#define fexp2(x) exp2f(x)
#endif

__device__ __forceinline__ float bf2f(ush u) {
    union { unsigned int i; float f; } v; v.i = ((unsigned int)u) << 16; return v.f;
}
__device__ __forceinline__ ush f2bf(float f) {
    union { float f; unsigned int i; } v; v.f = f;
    unsigned int x = v.i;
    return (ush)((x + 0x7FFFu + ((x >> 16) & 1u)) >> 16);  // RNE
}
__device__ __forceinline__ unsigned int pk2(float a, float b) {
    union { __hip_bfloat162 v; unsigned int u; } c;
    c.v = __float22bfloat162_rn(make_float2(a, b));  // lo=a, hi=b
    return c.u;
}
__device__ __forceinline__ float rcpf(float x) { return __builtin_amdgcn_rcpf(x); }

// ---- wprep: repack W_ih and W_hh into per-wave frag layout, scale-folded ---
// frag order n = gate*2 + sloc; element e = ((w*6 + n)*8 + ks)*512 + lane*8 + j
#define NWR 196608   // 768*256
__global__ __launch_bounds__(256) void wprep(const float* __restrict__ Wih,
                                             const float* __restrict__ Whh,
                                             ush* __restrict__ Wir,
                                             ush* __restrict__ Wr) {
    int idx = blockIdx.x * 256 + threadIdx.x;
    const float* src = (idx < NWR) ? Whh : Wih;
    ush* dst         = (idx < NWR) ? Wr  : Wir;
    int e = (idx < NWR) ? idx : idx - NWR;
    int w    = e / 24576, r1 = e % 24576;   // wave
    int n    = r1 / 4096,  r2 = r1 % 4096;  // frag = gate*2 + sloc
    int ks   = r2 / 512,   r3 = r2 % 512;
    int lane = r3 >> 3,    j  = r3 & 7;
    int l16 = lane & 15, quad = lane >> 4;
    int gate = n >> 1, sloc = n & 1;
    int srow = gate * 256 + (2 * w + sloc) * 16 + l16;
    int scol = ks * 32 + quad * 8 + j;
    float scl = (gate < 2) ? -L2E : 2.f * L2E;
    dst[e] = f2bf(src[srow * 256 + scol] * scl);
}

// ---- fused kernel ----------------------------------------------------------
__global__ __launch_bounds__(512, 2) void rnn_fused(const float* __restrict__ x,
                                                    const ush* __restrict__ Wir,
                                                    const ush* __restrict__ Wr,
                                                    const float* __restrict__ bih,
                                                    const float* __restrict__ bhh,
                                                    float* __restrict__ out) {
    __shared__ __align__(16) ush xs[48 * HS];       // 25,344 B  staged x (bf16)
    __shared__ unsigned int grz[NROW * GRS];        // 48,504 B
    __shared__ __align__(16) ush gn[NROW * GNS];    // 24,816 B
    __shared__ __align__(16) ush hl[2][MT * HS];    // 33,792 B  (tot 132,456)

    int tid  = threadIdx.x;
    int wave = tid >> 6, lane = tid & 63;
    int l16  = lane & 15, quad = lane >> 4, quad4 = quad * 4;
    int p0   = blockIdx.x * MT;
    int bb   = p0 >> 10, lb = p0 & 1023;
    int base = wave * 32 + l16;               // thread's first hidden col

    // ---- stage x rows j=0..47 (token lb-15+j, zero-padded) + zero h[0] -----
    {
        const float4* x4 = (const float4*)x;
        for (int idx = tid; idx < 48 * 64; idx += 512) {
            int j = idx >> 6, c = idx & 63;
            int tok = lb - 15 + j;
            float4 v = make_float4(0.f, 0.f, 0.f, 0.f);
            if (tok >= 0 && tok < L_) v = x4[(size_t)((bb << 10) + tok) * 64 + c];
            *(uint2*)(xs + j * HS + c * 4) = make_uint2(pk2(v.x, v.y), pk2(v.z, v.w));
        }
        for (int idx = tid; idx < MT * HS / 2; idx += 512)
            ((unsigned int*)(&hl[0][0]))[idx] = 0u;
    }
    __syncthreads();

    // ---- in-block gi GEMM: 48 rows x (6 col-frags for this wave) -----------
    {
        floatx4 gacc[3][6];  // [m-tile][frag = gate*2 + sl]
#pragma unroll
        for (int sl = 0; sl < 2; sl++) {
            int cs = base + sl * 16;
            float ir = -L2E * (bih[cs] + bhh[cs]);
            float iz = -L2E * (bih[256 + cs] + bhh[256 + cs]);
            float in_ = 2.f * L2E * bih[512 + cs];
#pragma unroll
            for (int mt = 0; mt < 3; mt++) {
                gacc[mt][0 + sl] = (floatx4){ir, ir, ir, ir};
                gacc[mt][2 + sl] = (floatx4){iz, iz, iz, iz};
                gacc[mt][4 + sl] = (floatx4){in_, in_, in_, in_};
            }
        }
        const ush* wp = Wir + (size_t)wave * 24576 + lane * 8;
#pragma unroll
        for (int ks = 0; ks < 8; ks++) {
            bf16x8 bw[6];
#pragma unroll
            for (int n = 0; n < 6; n++)
                bw[n] = *(const bf16x8*)(wp + ((n * 8 + ks) << 9));
#pragma unroll
            for (int mt = 0; mt < 3; mt++) {
                bf16x8 af = *(const bf16x8*)(xs + (mt * 16 + l16) * HS + ks * 32 + quad * 8);
#pragma unroll
                for (int n = 0; n < 6; n++)
                    gacc[mt][n] = __builtin_amdgcn_mfma_f32_16x16x32_bf16(
                        af, bw[n], gacc[mt][n], 0, 0, 0);
            }
        }
        // pack into grz/gn (C/D: col=l16 -> cs, row=quad4+r -> window row)
#pragma unroll
        for (int mt = 0; mt < 3; mt++)
#pragma unroll
            for (int sl = 0; sl < 2; sl++) {
                int cs = base + sl * 16;
#pragma unroll
                for (int r = 0; r < 4; r++) {
                    int j = mt * 16 + quad4 + r;
                    if (j < NROW) {
                        grz[j * GRS + cs] = pk2(gacc[mt][0 + sl][r], gacc[mt][2 + sl][r]);
                        gn[j * GNS + cs]  = f2bf(gacc[mt][4 + sl][r]);
                    }
                }
            }
    }

    // ---- W_hh fragments (scaled) -> 192 regs, held across all 16 steps -----
    bf16x8 wf[6][8];
    {
        const ush* wp = Wr + (size_t)wave * 24576 + lane * 8;
#pragma unroll
        for (int n = 0; n < 6; n++)
#pragma unroll
            for (int ks = 0; ks < 8; ks++)
                wf[n][ks] = *(const bf16x8*)(wp + ((n * 8 + ks) << 9));
    }
    float bn0 = 2.f * L2E * bhh[512 + base];
    float bn1 = 2.f * L2E * bhh[512 + base + 16];
    float hreg[16];
#pragma unroll
    for (int q = 0; q < 16; q++) hreg[q] = 0.f;
    __syncthreads();  // gi writes + h[0] zero visible

    // ---- GRU loop: one barrier per step ------------------------------------
    for (int t = 0; t < K_; t++) {
        const ush* hc  = &hl[t & 1][0];
        ush*       hnx = &hl[(t + 1) & 1][0];
#pragma unroll
        for (int T = 0; T < 2; T++) {
#pragma unroll
            for (int sl = 0; sl < 2; sl++) {
                int col = base + sl * 16;
                int r0  = T * 16 + quad4 + t;
                unsigned int c0 = grz[(r0 + 0) * GRS + col];
                unsigned int c1 = grz[(r0 + 1) * GRS + col];
                unsigned int c2 = grz[(r0 + 2) * GRS + col];
                unsigned int c3 = grz[(r0 + 3) * GRS + col];
                float bn = sl ? bn1 : bn0;
                floatx4 a0 = (floatx4){0.f, 0.f, 0.f, 0.f};
                floatx4 a1 = (floatx4){0.f, 0.f, 0.f, 0.f};
                floatx4 a2 = (floatx4){bn, bn, bn, bn};
                const ush* ha = hc + (T * 16 + l16) * HS + quad * 8;
#pragma unroll
                for (int ks = 0; ks < 8; ks++) {
                    bf16x8 af = *(const bf16x8*)(ha + ks * 32);
                    a0 = __builtin_amdgcn_mfma_f32_16x16x32_bf16(af, wf[0 + sl][ks], a0, 0, 0, 0);
                    a1 = __builtin_amdgcn_mfma_f32_16x16x32_bf16(af, wf[2 + sl][ks], a1, 0, 0, 0);
                    a2 = __builtin_amdgcn_mfma_f32_16x16x32_bf16(af, wf[4 + sl][ks], a2, 0, 0, 0);
                }
                unsigned int cc[4] = {c0, c1, c2, c3};
                int hb = (T * 16 + quad4) * HS + col;
#pragma unroll
                for (int r = 0; r < 4; r++) {
                    float ar = a0[r] + __uint_as_float(cc[r] << 16);
                    float az = a1[r] + __uint_as_float(cc[r] & 0xffff0000u);
                    float rg = rcpf(1.f + fexp2(ar));   // sigmoid (pre-scaled -log2e)
                    float zg = rcpf(1.f + fexp2(az));
                    float u  = bf2f(gn[(r0 + r) * GNS + col]) + rg * a2[r];
                    float ng = 1.f - 2.f * rcpf(fexp2(u) + 1.f);  // tanh (pre-scaled)
                    int q = T * 8 + sl * 4 + r;
                    float hv = ng + zg * (hreg[q] - ng);
                    hreg[q] = hv;
                    hnx[hb + r * HS] = f2bf(hv);
                }
            }
        }
        __syncthreads();
    }
    // ---- final h -> out (fp32), own cells ----------------------------------
#pragma unroll
    for (int T = 0; T < 2; T++)
#pragma unroll
        for (int sl = 0; sl < 2; sl++)
#pragma unroll
            for (int r = 0; r < 4; r++) {
                int row = T * 16 + quad4 + r, col = base + sl * 16;
                out[(size_t)(p0 + row) * H_ + col] = hreg[T * 8 + sl * 4 + r];
            }
}

extern "C" void kernel_launch(void* const* d_in, const int* in_sizes, int n_in,
                              void* d_out, int out_size, void* d_ws, size_t ws_size,
                              hipStream_t stream) {
    const float* x    = (const float*)d_in[0];
    const float* W_ih = (const float*)d_in[1];
    const float* W_hh = (const float*)d_in[2];
    const float* b_ih = (const float*)d_in[3];
    const float* b_hh = (const float*)d_in[4];
    float* out = (float*)d_out;

    // ws layout (bytes): Wir 393,216 | Wr 393,216  (scaled, wave-blocked)
    char* ws = (char*)d_ws;
    ush* Wir = (ush*)ws;
    ush* Wr  = (ush*)(ws + 393216);

    wprep<<<2 * NWR / 256, 256, 0, stream>>>(W_ih, W_hh, Wir, Wr);
    rnn_fused<<<B_ * L_ / MT, 512, 0, stream>>>(x, Wir, Wr, b_ih, b_hh, out);
}